// Round 3
// baseline (617.362 us; speedup 1.0000x reference)
//
#include <hip/hip_runtime.h>

// Problem constants (B=2, L=16, D=4, K=2, N_IN=8, N_OUT=8, NC=3)
#define NSITES (2 * 16 * 16 * 16 * 16)          // 131072 sites
// W:     site-stride 72  floats (8 ch * 3*3), site base 288 B (16B aligned)
// U_PT:  site-stride 180 floats (4 mu * 5 ik * 3*3)
// omega: flat [i][j][mu][ik] = i*160 + j*20 + mu*5 + ik  (1280 floats)
// out:   site-stride 72 floats

// LDS omega layout: [mu][ik][j][i], mu-stride padded to 328 floats
// (328*4B = 1312B -> 8-bank offset per mu -> conflict-free b128 reads)
#define OM_MU_STRIDE 328

__global__ __launch_bounds__(256, 4) void lconv_kernel(
    const float* __restrict__ W, const float* __restrict__ U_PT,
    const float* __restrict__ omega, float* __restrict__ out)
{
    __shared__ float s_om[4 * OM_MU_STRIDE];
    for (int t = threadIdx.x; t < 1280; t += 256) {
        const int i  = t / 160;
        const int r  = t - i * 160;
        const int j  = r / 20;
        const int r2 = r - j * 20;
        const int m  = r2 / 5;
        const int ik = r2 - m * 5;
        s_om[m * OM_MU_STRIDE + (ik * 8 + j) * 8 + i] = omega[t];
    }
    __syncthreads();

    // XCD-aware bijective swizzle: 2048 blocks, 8 XCDs, 256-block chunks.
    const int bid  = ((int)blockIdx.x & 7) * ((int)gridDim.x >> 3)
                   + ((int)blockIdx.x >> 3);
    const int idx  = bid * 256 + (int)threadIdx.x;
    const int s    = idx >> 2;        // site
    const int mu   = idx & 3;         // this thread's axis
    const int sh   = 12 - 4 * mu;     // bit position of x_mu in s
    const int x    = (s >> sh) & 15;

    const float* __restrict__ Ub  = U_PT + (size_t)s * 180 + (size_t)mu * 45;
    const float* __restrict__ omt = s_om + mu * OM_MU_STRIDE;

    float acc[8][9];
#pragma unroll
    for (int i = 0; i < 8; ++i)
#pragma unroll
        for (int e = 0; e < 9; ++e) acc[i][e] = 0.0f;

#pragma unroll 1
    for (int ik = 0; ik < 5; ++ik) {
        const int k = ik - 2;
        // U (3x3) for (mu, ik): 9 contiguous floats
        float U[9];
#pragma unroll
        for (int e = 0; e < 9; ++e) U[e] = Ub[ik * 9 + e];

        // neighbor site along mu: x_mu -> (x_mu + k) mod 16
        const int ns = s + ((((x + k + 16) & 15) - x) << sh);
        const float4* __restrict__ Wn4 =
            reinterpret_cast<const float4*>(W + (size_t)ns * 72);

#pragma unroll
        for (int jh = 0; jh < 2; ++jh) {
            // 4 channels' W (36 floats, 16B-aligned float4s)
            float Wl[36];
#pragma unroll
            for (int q = 0; q < 9; ++q) {
                const float4 v = Wn4[jh * 9 + q];
                Wl[q * 4 + 0] = v.x; Wl[q * 4 + 1] = v.y;
                Wl[q * 4 + 2] = v.z; Wl[q * 4 + 3] = v.w;
            }
#pragma unroll
            for (int jj = 0; jj < 4; ++jj) {
                const int j = jh * 4 + jj;
                // omega column for this (mu, ik, j): 8 i-values, 2x b128
                const float4 w0 = *reinterpret_cast<const float4*>(
                                      omt + (ik * 8 + j) * 8);
                const float4 w1 = *reinterpret_cast<const float4*>(
                                      omt + (ik * 8 + j) * 8 + 4);
                const float w[8] = {w0.x, w0.y, w0.z, w0.w,
                                    w1.x, w1.y, w1.z, w1.w};
                // sandwich element-wise: row a of U*W_j, then element (a,b)
#pragma unroll
                for (int a = 0; a < 3; ++a) {
                    float uw0 = fmaf(U[a * 3 + 0], Wl[jj * 9 + 0],
                                fmaf(U[a * 3 + 1], Wl[jj * 9 + 3],
                                     U[a * 3 + 2] * Wl[jj * 9 + 6]));
                    float uw1 = fmaf(U[a * 3 + 0], Wl[jj * 9 + 1],
                                fmaf(U[a * 3 + 1], Wl[jj * 9 + 4],
                                     U[a * 3 + 2] * Wl[jj * 9 + 7]));
                    float uw2 = fmaf(U[a * 3 + 0], Wl[jj * 9 + 2],
                                fmaf(U[a * 3 + 1], Wl[jj * 9 + 5],
                                     U[a * 3 + 2] * Wl[jj * 9 + 8]));
#pragma unroll
                    for (int b2 = 0; b2 < 3; ++b2) {
                        const float m = fmaf(uw0, U[b2 * 3 + 0],
                                        fmaf(uw1, U[b2 * 3 + 1],
                                             uw2 * U[b2 * 3 + 2]));
#pragma unroll
                        for (int i = 0; i < 8; ++i)
                            acc[i][a * 3 + b2] =
                                fmaf(w[i], m, acc[i][a * 3 + b2]);
                    }
                }
            }
        }
    }

    // reduce the 4 mu-partials within each lane group of 4
#pragma unroll
    for (int i = 0; i < 8; ++i)
#pragma unroll
        for (int e = 0; e < 9; ++e) {
            float v = acc[i][e];
            v += __shfl_xor(v, 1);
            v += __shfl_xor(v, 2);
            acc[i][e] = v;
        }

    // lane mu==0 of each group writes the full 72-float site block
    if (mu == 0) {
        float4* __restrict__ o4 = reinterpret_cast<float4*>(out + (size_t)s * 72);
#pragma unroll
        for (int q = 0; q < 18; ++q) {
            const int f = q * 4;
            o4[q] = make_float4(acc[(f + 0) / 9][(f + 0) % 9],
                                acc[(f + 1) / 9][(f + 1) % 9],
                                acc[(f + 2) / 9][(f + 2) % 9],
                                acc[(f + 3) / 9][(f + 3) % 9]);
        }
    }
}

extern "C" void kernel_launch(void* const* d_in, const int* in_sizes, int n_in,
                              void* d_out, int out_size, void* d_ws, size_t ws_size,
                              hipStream_t stream) {
    const float* W   = (const float*)d_in[0];
    const float* U   = (const float*)d_in[1];
    const float* om  = (const float*)d_in[2];
    float*       out = (float*)d_out;

    const int block = 256;
    const int grid  = (NSITES * 4) / block;   // 2048 blocks
    hipLaunchKernelGGL(lconv_kernel, dim3(grid), dim3(block), 0, stream,
                       W, U, om, out);
}

// Round 4
// 165.012 us; speedup vs baseline: 3.7413x; 3.7413x over previous
//
#include <hip/hip_runtime.h>

// Problem constants (B=2, L=16, D=4, K=2, N_IN=8, N_OUT=8, NC=3)
#define NSITES (2 * 16 * 16 * 16 * 16)          // 131072 sites
// W:     site-stride 72  floats (8 ch * 3*3), base 288 B (16B aligned)
// U_PT:  site-stride 180 floats (4 mu * 5 ik * 3*3)
// omega: flat [i][j][mu][ik] = i*160 + j*20 + mu*5 + ik  (1280 floats)
// out:   site-stride 72 floats
//
// Identity used: sum_j omega[i,j] * U W_j U^T  ==  U * (sum_j omega[i,j] W_j) * U^T
// -> mix first (V_i = sum_j w_ij W_j), sandwich once per output channel.
// Thread decomposition: 8 threads per site = (ihalf, mu); each thread owns
// 4 output channels for one mu; mu-partials reduced by shfl_xor(1,2).

#define OM_MU_STRIDE 328   // [mu][ik][j][i] with mu-pad: 5*8*8=320 -> 328

__global__ __launch_bounds__(256) void lconv_kernel(
    const float* __restrict__ W, const float* __restrict__ U_PT,
    const float* __restrict__ omega, float* __restrict__ out)
{
    __shared__ float s_om[4 * OM_MU_STRIDE];
    for (int t = threadIdx.x; t < 1280; t += 256) {
        const int i  = t / 160;
        const int r  = t - i * 160;
        const int j  = r / 20;
        const int r2 = r - j * 20;
        const int m  = r2 / 5;
        const int ik = r2 - m * 5;
        s_om[m * OM_MU_STRIDE + ik * 64 + j * 8 + i] = omega[t];
    }
    __syncthreads();

    // XCD-aware bijective swizzle: 4096 blocks, 8 XCDs, 512-block chunks.
    const int bid = ((int)blockIdx.x & 7) * ((int)gridDim.x >> 3)
                  + ((int)blockIdx.x >> 3);
    const int idx = bid * 256 + (int)threadIdx.x;
    const int s   = idx >> 3;         // site (32 consecutive sites per block)
    const int ih  = (idx >> 2) & 1;   // output-channel half (i = ih*4 + i')
    const int mu  = idx & 3;          // axis
    const int sh  = 12 - 4 * mu;      // bit position of x_mu in s
    const int x   = (s >> sh) & 15;

    const float* __restrict__ Ub  = U_PT + (size_t)s * 180 + mu * 45;
    const float* __restrict__ omt = s_om + mu * OM_MU_STRIDE + ih * 4;

    float acc[4][9];
#pragma unroll
    for (int i = 0; i < 4; ++i)
#pragma unroll
        for (int e = 0; e < 9; ++e) acc[i][e] = 0.0f;

#pragma unroll 1
    for (int ik = 0; ik < 5; ++ik) {
        const int k = ik - 2;
        float U[9];
#pragma unroll
        for (int e = 0; e < 9; ++e) U[e] = Ub[ik * 9 + e];

        const int ns = s + ((((x + k + 16) & 15) - x) << sh);
        const float4* __restrict__ Wn4 =
            reinterpret_cast<const float4*>(W + (size_t)ns * 72);

        // V_i = sum_j omega[i,j,mu,ik] * W_j   (4 channels i = ih*4 + i')
        float V[4][9];
#pragma unroll
        for (int i = 0; i < 4; ++i)
#pragma unroll
            for (int e = 0; e < 9; ++e) V[i][e] = 0.0f;

#pragma unroll
        for (int j = 0; j < 8; ++j) {
            const int f4b = (j * 9) >> 2;   // channel j = floats j*9..j*9+8
            const int off = (j * 9) & 3;
            float Wf[12];
#pragma unroll
            for (int q = 0; q < 3; ++q) {
                const float4 v = Wn4[f4b + q];
                Wf[q * 4 + 0] = v.x; Wf[q * 4 + 1] = v.y;
                Wf[q * 4 + 2] = v.z; Wf[q * 4 + 3] = v.w;
            }
            const float4 w4 = *reinterpret_cast<const float4*>(
                                  omt + ik * 64 + j * 8);
            const float wv[4] = {w4.x, w4.y, w4.z, w4.w};
#pragma unroll
            for (int i = 0; i < 4; ++i)
#pragma unroll
                for (int e = 0; e < 9; ++e)
                    V[i][e] = fmaf(wv[i], Wf[off + e], V[i][e]);
        }

        // acc_i += U * V_i * U^T
#pragma unroll
        for (int i = 0; i < 4; ++i) {
#pragma unroll
            for (int a = 0; a < 3; ++a) {
                const float uw0 = fmaf(U[a * 3 + 0], V[i][0],
                                  fmaf(U[a * 3 + 1], V[i][3],
                                       U[a * 3 + 2] * V[i][6]));
                const float uw1 = fmaf(U[a * 3 + 0], V[i][1],
                                  fmaf(U[a * 3 + 1], V[i][4],
                                       U[a * 3 + 2] * V[i][7]));
                const float uw2 = fmaf(U[a * 3 + 0], V[i][2],
                                  fmaf(U[a * 3 + 1], V[i][5],
                                       U[a * 3 + 2] * V[i][8]));
#pragma unroll
                for (int b2 = 0; b2 < 3; ++b2)
                    acc[i][a * 3 + b2] =
                        fmaf(uw0, U[b2 * 3 + 0],
                        fmaf(uw1, U[b2 * 3 + 1],
                        fmaf(uw2, U[b2 * 3 + 2], acc[i][a * 3 + b2])));
            }
        }
    }

    // reduce the 4 mu-partials within each lane group of 4
#pragma unroll
    for (int i = 0; i < 4; ++i)
#pragma unroll
        for (int e = 0; e < 9; ++e) {
            float v = acc[i][e];
            v += __shfl_xor(v, 1);
            v += __shfl_xor(v, 2);
            acc[i][e] = v;
        }

    // lane mu==0 of each group writes its 36-float half-block (144B = 9 float4)
    if (mu == 0) {
        float4* __restrict__ o4 =
            reinterpret_cast<float4*>(out + (size_t)s * 72 + ih * 36);
#pragma unroll
        for (int q = 0; q < 9; ++q) {
            const int f = q * 4;
            o4[q] = make_float4(acc[(f + 0) / 9][(f + 0) % 9],
                                acc[(f + 1) / 9][(f + 1) % 9],
                                acc[(f + 2) / 9][(f + 2) % 9],
                                acc[(f + 3) / 9][(f + 3) % 9]);
        }
    }
}

extern "C" void kernel_launch(void* const* d_in, const int* in_sizes, int n_in,
                              void* d_out, int out_size, void* d_ws, size_t ws_size,
                              hipStream_t stream) {
    const float* W   = (const float*)d_in[0];
    const float* U   = (const float*)d_in[1];
    const float* om  = (const float*)d_in[2];
    float*       out = (float*)d_out;

    const int block = 256;
    const int grid  = (NSITES * 8) / block;   // 4096 blocks
    hipLaunchKernelGGL(lconv_kernel, dim3(grid), dim3(block), 0, stream,
                       W, U, om, out);
}